// Round 1
// baseline (411.254 us; speedup 1.0000x reference)
//
#include <hip/hip_runtime.h>
#include <hip/hip_bf16.h>
#include <stdint.h>

// ---------------------------------------------------------------------------
// W8A16 linear: out[M,N] = (A[M,K] fp32) x (W[N,K] int8->bf16)^T * scales[N] + bias[N]
// M = B*S = 8192, N = 4096, K = 4096 (all multiples of tile sizes).
// Strategy: convert A->bf16 and W->bf16 into d_ws, then m97-structure bf16 MFMA GEMM.
// ---------------------------------------------------------------------------

typedef __attribute__((ext_vector_type(8))) short bf16x8;
typedef __attribute__((ext_vector_type(4))) float f32x4;
typedef __attribute__((ext_vector_type(8))) unsigned short u16x8;

__device__ __forceinline__ unsigned short f2bf(float x) {
  union { float f; unsigned u; } v; v.f = x;
  unsigned u = v.u;
  return (unsigned short)((u + 0x7FFFu + ((u >> 16) & 1u)) >> 16); // RNE
}

// ---- prepass: A fp32 -> bf16, 8 elems/thread ------------------------------
__global__ __launch_bounds__(256) void cvt_a_kernel(const float* __restrict__ in,
                                                    unsigned short* __restrict__ out) {
  long i = (long)blockIdx.x * 256 + threadIdx.x;  // handles elems [8i, 8i+8)
  const float4* in4 = (const float4*)in;
  float4 a = in4[2 * i];
  float4 b = in4[2 * i + 1];
  u16x8 r;
  r[0] = f2bf(a.x); r[1] = f2bf(a.y); r[2] = f2bf(a.z); r[3] = f2bf(a.w);
  r[4] = f2bf(b.x); r[5] = f2bf(b.y); r[6] = f2bf(b.z); r[7] = f2bf(b.w);
  ((u16x8*)out)[i] = r;
}

// ---- prepass: W int32 -> bf16 (int8 values, exact in bf16), 8/thread ------
__global__ __launch_bounds__(256) void cvt_w_kernel(const int* __restrict__ in,
                                                    unsigned short* __restrict__ out) {
  long i = (long)blockIdx.x * 256 + threadIdx.x;
  int4 a = ((const int4*)in)[2 * i];
  int4 b = ((const int4*)in)[2 * i + 1];
  u16x8 r;
  r[0] = f2bf((float)a.x); r[1] = f2bf((float)a.y);
  r[2] = f2bf((float)a.z); r[3] = f2bf((float)a.w);
  r[4] = f2bf((float)b.x); r[5] = f2bf((float)b.y);
  r[6] = f2bf((float)b.z); r[7] = f2bf((float)b.w);
  ((u16x8*)out)[i] = r;
}

// ---- async global -> LDS, 16B per lane ------------------------------------
__device__ __forceinline__ void gl_lds16(const void* g, void* l) {
  __builtin_amdgcn_global_load_lds(
      (const __attribute__((address_space(1))) void*)g,
      (__attribute__((address_space(3))) void*)l,
      16, 0, 0);
}

// ---- main GEMM: 128x128 tile, BK=32, 256 threads = 4 waves (2x2 of 64x64) -
#define BM 128
#define BN 128
#define BK 32

__global__ __launch_bounds__(256) void gemm_bf16_kernel(
    const unsigned short* __restrict__ A,   // [M,K] bf16
    const unsigned short* __restrict__ Wt,  // [N,K] bf16
    const float* __restrict__ scales,       // [N]
    const float* __restrict__ bias,         // [N]
    float* __restrict__ out,                // [M,N]
    int M, int N, int K) {
  __shared__ unsigned short sA[BM * BK];  // 8 KB, linear (global_load_lds dest)
  __shared__ unsigned short sB[BN * BK];  // 8 KB

  const int tid = threadIdx.x;
  const int lane = tid & 63;
  const int w = tid >> 6;
  const int bm = blockIdx.y * BM;
  const int bn = blockIdx.x * BN;

  const int r = lane & 15;   // fragment row/col within 16
  const int q = lane >> 4;   // k-group (0..3)

  const int m_off = (w >> 1) * 64;  // wave's 64x64 sub-tile
  const int n_off = (w & 1) * 64;

  f32x4 acc[4][4] = {};

  for (int k0 = 0; k0 < K; k0 += BK) {
    // stage A-tile [128][32] and B-tile [128][32]; chunk c = 16B, row = c/4
#pragma unroll
    for (int j = 0; j < 2; ++j) {
      int c = j * 256 + tid;
      int row = c >> 2;
      int kg = c & 3;
      gl_lds16(A + (size_t)(bm + row) * K + k0 + kg * 8, (char*)sA + c * 16);
      gl_lds16(Wt + (size_t)(bn + row) * K + k0 + kg * 8, (char*)sB + c * 16);
    }
    __syncthreads();  // compiler emits vmcnt(0) drain before barrier

    bf16x8 af[4], bg[4];
#pragma unroll
    for (int mi = 0; mi < 4; ++mi)
      af[mi] = *(const bf16x8*)&sA[(m_off + mi * 16 + r) * BK + q * 8];
#pragma unroll
    for (int ni = 0; ni < 4; ++ni)
      bg[ni] = *(const bf16x8*)&sB[(n_off + ni * 16 + r) * BK + q * 8];

#pragma unroll
    for (int mi = 0; mi < 4; ++mi)
#pragma unroll
      for (int ni = 0; ni < 4; ++ni)
        acc[mi][ni] = __builtin_amdgcn_mfma_f32_16x16x32_bf16(
            af[mi], bg[ni], acc[mi][ni], 0, 0, 0);

    __syncthreads();
  }

  // epilogue: out = acc * scales[col] + bias[col]
  float sc[4], bs[4];
#pragma unroll
  for (int ni = 0; ni < 4; ++ni) {
    int col = bn + n_off + ni * 16 + r;
    sc[ni] = scales[col];
    bs[ni] = bias[col];
  }
#pragma unroll
  for (int mi = 0; mi < 4; ++mi)
#pragma unroll
    for (int ni = 0; ni < 4; ++ni)
#pragma unroll
      for (int i = 0; i < 4; ++i) {
        int grow = bm + m_off + mi * 16 + q * 4 + i;  // C/D row = (lane>>4)*4+i
        int gcol = bn + n_off + ni * 16 + r;          // C/D col = lane&15
        out[(size_t)grow * N + gcol] = acc[mi][ni][i] * sc[ni] + bs[ni];
      }
}

// ---- fallback (only if ws too small; correct but slow) --------------------
__global__ __launch_bounds__(256) void naive_kernel(
    const float* __restrict__ A, const int* __restrict__ W8,
    const float* __restrict__ scales, const float* __restrict__ bias,
    float* __restrict__ out, int M, int N, int K) {
  long idx = (long)blockIdx.x * 256 + threadIdx.x;
  if (idx >= (long)M * N) return;
  int m = (int)(idx / N), n = (int)(idx % N);
  const float* a = A + (size_t)m * K;
  const int* wv = W8 + (size_t)n * K;
  float s = 0.f;
  for (int k = 0; k < K; ++k) s += a[k] * (float)wv[k];
  out[idx] = s * scales[n] + bias[n];
}

extern "C" void kernel_launch(void* const* d_in, const int* in_sizes, int n_in,
                              void* d_out, int out_size, void* d_ws, size_t ws_size,
                              hipStream_t stream) {
  const float* A = (const float*)d_in[0];
  const int* W8 = (const int*)d_in[1];     // int8 values delivered as int32
  const float* scales = (const float*)d_in[2];
  const float* bias = (const float*)d_in[3];
  float* out = (float*)d_out;

  const int N = in_sizes[2];               // 4096
  const int K = in_sizes[1] / N;           // 4096
  const int M = in_sizes[0] / K;           // 8192

  size_t a_bytes = (size_t)M * K * 2;
  size_t w_bytes = (size_t)N * K * 2;

  if (ws_size < a_bytes + w_bytes) {
    long total = (long)M * N;
    naive_kernel<<<(unsigned)((total + 255) / 256), 256, 0, stream>>>(
        A, W8, scales, bias, out, M, N, K);
    return;
  }

  unsigned short* Abf = (unsigned short*)d_ws;
  unsigned short* Wbf = (unsigned short*)((char*)d_ws + a_bytes);

  long nA = (long)M * K;
  long nW = (long)N * K;
  cvt_a_kernel<<<(unsigned)(nA / 2048), 256, 0, stream>>>(A, Abf);
  cvt_w_kernel<<<(unsigned)(nW / 2048), 256, 0, stream>>>(W8, Wbf);

  dim3 grid(N / BN, M / BM);  // 32 x 64 = 2048 blocks
  gemm_bf16_kernel<<<grid, 256, 0, stream>>>(Abf, Wbf, scales, bias, out, M, N, K);
}

// Round 2
// 309.310 us; speedup vs baseline: 1.3296x; 1.3296x over previous
//
#include <hip/hip_runtime.h>
#include <hip/hip_bf16.h>
#include <stdint.h>

// ---------------------------------------------------------------------------
// W8A16 linear: out[M,N] = (A[M,K] fp32) x (W[N,K] int8->bf16)^T * scales[N] + bias[N]
// M=8192, N=4096, K=4096.  Prepass converts A,W -> bf16 in d_ws, then a
// 256x256-tile 8-phase deep-pipelined bf16 MFMA GEMM (T1+T2+T3+T4+T5).
// ---------------------------------------------------------------------------

typedef __attribute__((ext_vector_type(8))) short bf16x8;
typedef __attribute__((ext_vector_type(4))) float f32x4;
typedef __attribute__((ext_vector_type(8))) unsigned short u16x8;

__device__ __forceinline__ unsigned short f2bf(float x) {
  union { float f; unsigned u; } v; v.f = x;
  unsigned u = v.u;
  return (unsigned short)((u + 0x7FFFu + ((u >> 16) & 1u)) >> 16); // RNE
}

// ---- prepass: A fp32 -> bf16, 8 elems/thread ------------------------------
__global__ __launch_bounds__(256) void cvt_a_kernel(const float* __restrict__ in,
                                                    unsigned short* __restrict__ out) {
  long i = (long)blockIdx.x * 256 + threadIdx.x;
  const float4* in4 = (const float4*)in;
  float4 a = in4[2 * i];
  float4 b = in4[2 * i + 1];
  u16x8 r;
  r[0] = f2bf(a.x); r[1] = f2bf(a.y); r[2] = f2bf(a.z); r[3] = f2bf(a.w);
  r[4] = f2bf(b.x); r[5] = f2bf(b.y); r[6] = f2bf(b.z); r[7] = f2bf(b.w);
  ((u16x8*)out)[i] = r;
}

// ---- prepass: W int32 -> bf16 (int8 values exact in bf16), 8/thread -------
__global__ __launch_bounds__(256) void cvt_w_kernel(const int* __restrict__ in,
                                                    unsigned short* __restrict__ out) {
  long i = (long)blockIdx.x * 256 + threadIdx.x;
  int4 a = ((const int4*)in)[2 * i];
  int4 b = ((const int4*)in)[2 * i + 1];
  u16x8 r;
  r[0] = f2bf((float)a.x); r[1] = f2bf((float)a.y);
  r[2] = f2bf((float)a.z); r[3] = f2bf((float)a.w);
  r[4] = f2bf((float)b.x); r[5] = f2bf((float)b.y);
  r[6] = f2bf((float)b.z); r[7] = f2bf((float)b.w);
  ((u16x8*)out)[i] = r;
}

// ---- async global -> LDS, 16B per lane ------------------------------------
__device__ __forceinline__ void gl_lds16(const void* g, void* l) {
  __builtin_amdgcn_global_load_lds(
      (const __attribute__((address_space(1))) void*)g,
      (__attribute__((address_space(3))) void*)l,
      16, 0, 0);
}

#define WAIT_LGKM0() do { asm volatile("s_waitcnt lgkmcnt(0)" ::: "memory"); \
                          __builtin_amdgcn_sched_barrier(0); } while (0)
#define WAIT_VM(N)   asm volatile("s_waitcnt vmcnt(" #N ")" ::: "memory")
#define BAR()        do { asm volatile("" ::: "memory"); \
                          __builtin_amdgcn_s_barrier(); \
                          asm volatile("" ::: "memory"); } while (0)

// ---- 256x256 8-phase GEMM -------------------------------------------------
#define BM 256
#define BN 256
#define BKT 64
#define HELEMS (128 * 64)   // one half-tile: 128 rows x 64 k-elems = 16 KB

// T2 swizzle on read: within a half buffer, byte ^= ((row&7)<<4)
__device__ __forceinline__ bf16x8 ld_frag(const unsigned short* half_base,
                                          int rowInHalf, int colByte) {
  int X = rowInHalf * 128 + colByte;
  int Y = X ^ (((X >> 7) & 7) << 4);
  return *(const bf16x8*)((const char*)half_base + Y);
}

template <int MI0>
__device__ __forceinline__ void read_aq(bf16x8 (&dst)[2][2],
                                        const unsigned short* sAh, int r, int q4) {
#pragma unroll
  for (int m = 0; m < 2; ++m)
#pragma unroll
    for (int kk = 0; kk < 2; ++kk)
      dst[m][kk] = ld_frag(sAh, (MI0 + m) * 16 + r, kk * 64 + q4 * 16);
}

template <int MI0>
__device__ __forceinline__ void mfma_quad(f32x4 (&acc)[8][4],
                                          const bf16x8 (&a)[2][2],
                                          const bf16x8 (&b)[4][2]) {
  __builtin_amdgcn_s_setprio(1);
#pragma unroll
  for (int m = 0; m < 2; ++m)
#pragma unroll
    for (int ni = 0; ni < 4; ++ni)
#pragma unroll
      for (int kk = 0; kk < 2; ++kk)
        acc[MI0 + m][ni] = __builtin_amdgcn_mfma_f32_16x16x32_bf16(
            a[m][kk], b[ni][kk], acc[MI0 + m][ni], 0, 0, 0);
  __builtin_amdgcn_s_setprio(0);
}

__global__ __launch_bounds__(512, 2) void gemm8_kernel(
    const unsigned short* __restrict__ A,   // [M,K] bf16
    const unsigned short* __restrict__ Wt,  // [N,K] bf16
    const float* __restrict__ scales,       // [N]
    const float* __restrict__ bias,         // [N]
    float* __restrict__ out,                // [M,N] fp32
    int M, int N, int K) {
  // [buf][A=0/B=1][half][128*64]
  __shared__ unsigned short lds[2][2][2][HELEMS];

  const int tid = threadIdx.x;
  const int lane = tid & 63;
  const int w = tid >> 6;      // wave 0..7
  const int wr = w >> 2;       // 0..1 (M)
  const int wc = w & 3;        // 0..3 (N)
  const int r = lane & 15;
  const int q4 = lane >> 4;

  const int NT = K / BKT;

  // T1: bijective XCD swizzle (grid is a multiple of 8 here: 32*16=512)
  const int nwg_m = M / BM;
  int bid = blockIdx.x;
  int nwg = gridDim.x;
  int swz = bid;
  if ((nwg & 7) == 0) swz = (bid & 7) * (nwg >> 3) + (bid >> 3);
  const int tile_m = swz % nwg_m;   // consecutive swz share tile_n -> B panel L2-hot
  const int tile_n = swz / nwg_m;
  const int bm = tile_m * BM;
  const int bn = tile_n * BN;

  // staging constants: chunk c = w*2+j covers rows c*8..c*8+7 of a half-tile;
  // lane l -> row c*8 + (l>>3); inverse-swizzled source granule (T2 write side)
  const int rl = lane >> 3;
  const int gs = (lane & 7) ^ (rl & 7);

  const unsigned short* Abase = A + (size_t)bm * K;
  const unsigned short* Bbase = Wt + (size_t)bn * K;

  auto STAGE = [&](unsigned short* ldsHalf, const unsigned short* gbase) {
    const unsigned short* g0 = gbase + (size_t)(w * 16 + rl) * K + gs * 8;
    unsigned short* l0 = ldsHalf + w * 1024 + lane * 8;  // linear dest
    gl_lds16(g0, l0);
    gl_lds16(g0 + (size_t)8 * K, l0 + 512);
  };

  // ---- prologue: tile0 (4 halves) then tile1 {B0,B1,A0} (3 halves) --------
  STAGE(&lds[0][0][0][0], Abase);
  STAGE(&lds[0][0][1][0], Abase + (size_t)128 * K);
  STAGE(&lds[0][1][0][0], Bbase);
  STAGE(&lds[0][1][1][0], Bbase + (size_t)128 * K);
  WAIT_VM(4);
  STAGE(&lds[1][1][0][0], Bbase + BKT);
  STAGE(&lds[1][1][1][0], Bbase + (size_t)128 * K + BKT);
  STAGE(&lds[1][0][0][0], Abase + BKT);
  WAIT_VM(6);
  BAR();

  bf16x8 bfr[4][2];
  bf16x8 a0[2][2], a1[2][2], a2[2][2], a3[2][2];
  f32x4 acc[8][4] = {};

  for (int u = 0; u < NT; ++u) {
    const int p = u & 1;
    const unsigned short* sAh = &lds[p][0][wr][0];
    const unsigned short* sBh = &lds[p][1][wc >> 1][0];
    const int rb = (wc & 1) * 64;

    // ---- phase 1: B frags + A quad0; stage tile u+1 A-half1 ----
#pragma unroll
    for (int ni = 0; ni < 4; ++ni)
#pragma unroll
      for (int kk = 0; kk < 2; ++kk)
        bfr[ni][kk] = ld_frag(sBh, rb + ni * 16 + r, kk * 64 + q4 * 16);
    read_aq<0>(a0, sAh, r, q4);
    if (u + 1 < NT)
      STAGE(&lds[p ^ 1][0][1][0], Abase + (size_t)128 * K + (size_t)(u + 1) * BKT);
    BAR();
    WAIT_LGKM0();
    mfma_quad<0>(acc, a0, bfr);
    BAR();

    // ---- phase 2: A quads 1,2; stage tile u+2 B-half0 (freed after p1) ----
    read_aq<2>(a1, sAh, r, q4);
    read_aq<4>(a2, sAh, r, q4);
    if (u + 2 < NT)
      STAGE(&lds[p][1][0][0], Bbase + (size_t)(u + 2) * BKT);
    BAR();
    WAIT_LGKM0();
    mfma_quad<2>(acc, a1, bfr);
    BAR();

    // ---- phase 3: A quad3; stage tile u+2 B-half1 ----
    read_aq<6>(a3, sAh, r, q4);
    if (u + 2 < NT)
      STAGE(&lds[p][1][1][0], Bbase + (size_t)128 * K + (size_t)(u + 2) * BKT);
    BAR();
    WAIT_LGKM0();
    mfma_quad<4>(acc, a2, bfr);
    BAR();

    // ---- phase 4: stage tile u+2 A-half0 (A reads done by p3); vmcnt ----
    if (u + 2 < NT)
      STAGE(&lds[p][0][0][0], Abase + (size_t)(u + 2) * BKT);
    if (u < NT - 1) {
      if (u + 2 < NT) { WAIT_VM(6); } else { WAIT_VM(0); }
    }
    BAR();
    WAIT_LGKM0();
    mfma_quad<6>(acc, a3, bfr);
    BAR();
  }

  // ---- epilogue: out = acc * scales + bias --------------------------------
  float sc[4], bs[4];
#pragma unroll
  for (int ni = 0; ni < 4; ++ni) {
    int col = bn + wc * 64 + ni * 16 + r;
    sc[ni] = scales[col];
    bs[ni] = bias[col];
  }
#pragma unroll
  for (int mi = 0; mi < 8; ++mi)
#pragma unroll
    for (int ni = 0; ni < 4; ++ni)
#pragma unroll
      for (int i = 0; i < 4; ++i) {
        int grow = bm + wr * 128 + mi * 16 + q4 * 4 + i;
        int gcol = bn + wc * 64 + ni * 16 + r;
        out[(size_t)grow * N + gcol] = acc[mi][ni][i] * sc[ni] + bs[ni];
      }
}

// ---- fallback (correct but slow) ------------------------------------------
__global__ __launch_bounds__(256) void naive_kernel(
    const float* __restrict__ A, const int* __restrict__ W8,
    const float* __restrict__ scales, const float* __restrict__ bias,
    float* __restrict__ out, int M, int N, int K) {
  long idx = (long)blockIdx.x * 256 + threadIdx.x;
  if (idx >= (long)M * N) return;
  int m = (int)(idx / N), n = (int)(idx % N);
  const float* a = A + (size_t)m * K;
  const int* wv = W8 + (size_t)n * K;
  float s = 0.f;
  for (int k = 0; k < K; ++k) s += a[k] * (float)wv[k];
  out[idx] = s * scales[n] + bias[n];
}

extern "C" void kernel_launch(void* const* d_in, const int* in_sizes, int n_in,
                              void* d_out, int out_size, void* d_ws, size_t ws_size,
                              hipStream_t stream) {
  const float* A = (const float*)d_in[0];
  const int* W8 = (const int*)d_in[1];
  const float* scales = (const float*)d_in[2];
  const float* bias = (const float*)d_in[3];
  float* out = (float*)d_out;

  const int N = in_sizes[2];
  const int K = in_sizes[1] / N;
  const int M = in_sizes[0] / K;

  size_t a_bytes = (size_t)M * K * 2;
  size_t w_bytes = (size_t)N * K * 2;

  bool tiled_ok = (M % BM == 0) && (N % BN == 0) && (K % BKT == 0) &&
                  (K / BKT >= 3) && (ws_size >= a_bytes + w_bytes);

  if (!tiled_ok) {
    long total = (long)M * N;
    naive_kernel<<<(unsigned)((total + 255) / 256), 256, 0, stream>>>(
        A, W8, scales, bias, out, M, N, K);
    return;
  }

  unsigned short* Abf = (unsigned short*)d_ws;
  unsigned short* Wbf = (unsigned short*)((char*)d_ws + a_bytes);

  long nA = (long)M * K;
  long nW = (long)N * K;
  cvt_a_kernel<<<(unsigned)(nA / 2048), 256, 0, stream>>>(A, Abf);
  cvt_w_kernel<<<(unsigned)(nW / 2048), 256, 0, stream>>>(W8, Wbf);

  unsigned nwg = (unsigned)((M / BM) * (N / BN));  // 512
  gemm8_kernel<<<nwg, 512, 0, stream>>>(Abf, Wbf, scales, bias, out, M, N, K);
}

// Round 4
// 299.417 us; speedup vs baseline: 1.3735x; 1.0330x over previous
//
#include <hip/hip_runtime.h>
#include <hip/hip_bf16.h>
#include <stdint.h>

// ---------------------------------------------------------------------------
// W8A16 linear: out[M,N] = (A[M,K] fp32) x (W[N,K] int8->bf16)^T * scales[N] + bias[N]
// M=8192, N=4096, K=4096.  Prepass converts A,W -> bf16 in d_ws, then a
// 256x256-tile 8-phase deep-pipelined bf16 MFMA GEMM (T1+T2+T3+T4+T5).
// R4 = R2's proven-correct schedule + supertile XCD swizzle (A L2-resident,
// staging hits L2/L3 instead of HBM) + lgkmcnt(8) pre-barrier hint.
// ---------------------------------------------------------------------------

typedef __attribute__((ext_vector_type(8))) short bf16x8;
typedef __attribute__((ext_vector_type(4))) float f32x4;
typedef __attribute__((ext_vector_type(8))) unsigned short u16x8;

__device__ __forceinline__ unsigned short f2bf(float x) {
  union { float f; unsigned u; } v; v.f = x;
  unsigned u = v.u;
  return (unsigned short)((u + 0x7FFFu + ((u >> 16) & 1u)) >> 16); // RNE
}

// ---- prepass: A fp32 -> bf16, 8 elems/thread ------------------------------
__global__ __launch_bounds__(256) void cvt_a_kernel(const float* __restrict__ in,
                                                    unsigned short* __restrict__ out) {
  long i = (long)blockIdx.x * 256 + threadIdx.x;
  const float4* in4 = (const float4*)in;
  float4 a = in4[2 * i];
  float4 b = in4[2 * i + 1];
  u16x8 r;
  r[0] = f2bf(a.x); r[1] = f2bf(a.y); r[2] = f2bf(a.z); r[3] = f2bf(a.w);
  r[4] = f2bf(b.x); r[5] = f2bf(b.y); r[6] = f2bf(b.z); r[7] = f2bf(b.w);
  ((u16x8*)out)[i] = r;
}

// ---- prepass: W int32 -> bf16 (int8 values exact in bf16), 8/thread -------
__global__ __launch_bounds__(256) void cvt_w_kernel(const int* __restrict__ in,
                                                    unsigned short* __restrict__ out) {
  long i = (long)blockIdx.x * 256 + threadIdx.x;
  int4 a = ((const int4*)in)[2 * i];
  int4 b = ((const int4*)in)[2 * i + 1];
  u16x8 r;
  r[0] = f2bf((float)a.x); r[1] = f2bf((float)a.y);
  r[2] = f2bf((float)a.z); r[3] = f2bf((float)a.w);
  r[4] = f2bf((float)b.x); r[5] = f2bf((float)b.y);
  r[6] = f2bf((float)b.z); r[7] = f2bf((float)b.w);
  ((u16x8*)out)[i] = r;
}

// ---- async global -> LDS, 16B per lane ------------------------------------
__device__ __forceinline__ void gl_lds16(const void* g, void* l) {
  __builtin_amdgcn_global_load_lds(
      (const __attribute__((address_space(1))) void*)g,
      (__attribute__((address_space(3))) void*)l,
      16, 0, 0);
}

#define WAIT_LGKM0() do { asm volatile("s_waitcnt lgkmcnt(0)" ::: "memory"); \
                          __builtin_amdgcn_sched_barrier(0); } while (0)
#define LGKM_HINT(N) asm volatile("s_waitcnt lgkmcnt(" #N ")" ::: "memory")
#define WAIT_VM(N)   asm volatile("s_waitcnt vmcnt(" #N ")" ::: "memory")
#define BAR()        do { asm volatile("" ::: "memory"); \
                          __builtin_amdgcn_s_barrier(); \
                          asm volatile("" ::: "memory"); } while (0)

// ---- 256x256 8-phase GEMM -------------------------------------------------
#define BM 256
#define BN 256
#define BKT 64
#define HELEMS (128 * 64)   // one half-tile: 128 rows x 64 k-elems = 16 KB

// T2 swizzle on read: within a half buffer, byte ^= ((row&7)<<4)
__device__ __forceinline__ bf16x8 ld_frag(const unsigned short* half_base,
                                          int rowInHalf, int colByte) {
  int X = rowInHalf * 128 + colByte;
  int Y = X ^ (((X >> 7) & 7) << 4);
  return *(const bf16x8*)((const char*)half_base + Y);
}

template <int MI0>
__device__ __forceinline__ void read_aq(bf16x8 (&dst)[2][2],
                                        const unsigned short* sAh, int r, int q4) {
#pragma unroll
  for (int m = 0; m < 2; ++m)
#pragma unroll
    for (int kk = 0; kk < 2; ++kk)
      dst[m][kk] = ld_frag(sAh, (MI0 + m) * 16 + r, kk * 64 + q4 * 16);
}

template <int MI0>
__device__ __forceinline__ void mfma_quad(f32x4 (&acc)[8][4],
                                          const bf16x8 (&a)[2][2],
                                          const bf16x8 (&b)[4][2]) {
  __builtin_amdgcn_s_setprio(1);
#pragma unroll
  for (int m = 0; m < 2; ++m)
#pragma unroll
    for (int ni = 0; ni < 4; ++ni)
#pragma unroll
      for (int kk = 0; kk < 2; ++kk)
        acc[MI0 + m][ni] = __builtin_amdgcn_mfma_f32_16x16x32_bf16(
            a[m][kk], b[ni][kk], acc[MI0 + m][ni], 0, 0, 0);
  __builtin_amdgcn_s_setprio(0);
}

__global__ __launch_bounds__(512, 2) void gemm8_kernel(
    const unsigned short* __restrict__ A,   // [M,K] bf16
    const unsigned short* __restrict__ Wt,  // [N,K] bf16
    const float* __restrict__ scales,       // [N]
    const float* __restrict__ bias,         // [N]
    float* __restrict__ out,                // [M,N] fp32
    int M, int N, int K) {
  // [buf][A=0/B=1][half][128*64]
  __shared__ unsigned short lds[2][2][2][HELEMS];

  const int tid = threadIdx.x;
  const int lane = tid & 63;
  const int w = tid >> 6;      // wave 0..7
  const int wr = w >> 2;       // 0..1 (M)
  const int wc = w & 3;        // 0..3 (N)
  const int r = lane & 15;
  const int q4 = lane >> 4;

  const int NT = K / BKT;

  // Block swizzle: supertile — per-XCD strip of 1 tile_m x 16 tile_n.
  // A panel per strip = 2 MB (L2-resident); B panels L3-shared across XCDs.
  const int nm = M / BM, nn_t = N / BN;
  const int nwg = gridDim.x;
  const int bid = blockIdx.x;
  int tile_m, tile_n;
  if (nm == 32 && nn_t == 16 && nwg == 512) {
    int xcd = bid & 7;
    int j = bid >> 3;        // 0..63
    int patch = j >> 4;      // 0..3
    int i = j & 15;          // 0..15
    tile_m = patch * 8 + xcd;
    tile_n = i;
  } else {
    int swz = bid;
    if ((nwg & 7) == 0) swz = (bid & 7) * (nwg >> 3) + (bid >> 3);
    tile_m = swz % nm;
    tile_n = swz / nm;
  }
  const int bm = tile_m * BM;
  const int bn = tile_n * BN;

  // staging: lane l -> row (w*16 + (l>>3)) of half-tile, inverse-swizzled
  // source granule (T2 write side); linear LDS dest for global_load_lds.
  const int rl = lane >> 3;
  const int gs = (lane & 7) ^ (rl & 7);

  const unsigned short* Abase = A + (size_t)bm * K;
  const unsigned short* Bbase = Wt + (size_t)bn * K;

  auto STAGE = [&](unsigned short* ldsHalf, const unsigned short* gbase) {
    const unsigned short* g0 = gbase + (size_t)(w * 16 + rl) * K + gs * 8;
    unsigned short* l0 = ldsHalf + w * 1024 + lane * 8;  // linear dest
    gl_lds16(g0, l0);
    gl_lds16(g0 + (size_t)8 * K, l0 + 512);
  };

  // ---- prologue: tile0 (4 halves) then tile1 {B0,B1,A0} (3 halves) --------
  STAGE(&lds[0][0][0][0], Abase);
  STAGE(&lds[0][0][1][0], Abase + (size_t)128 * K);
  STAGE(&lds[0][1][0][0], Bbase);
  STAGE(&lds[0][1][1][0], Bbase + (size_t)128 * K);
  WAIT_VM(4);
  STAGE(&lds[1][1][0][0], Bbase + BKT);
  STAGE(&lds[1][1][1][0], Bbase + (size_t)128 * K + BKT);
  STAGE(&lds[1][0][0][0], Abase + BKT);
  WAIT_VM(6);
  BAR();

  bf16x8 bfr[4][2];
  bf16x8 a0[2][2], a1[2][2], a2[2][2], a3[2][2];
  f32x4 acc[8][4] = {};

  for (int u = 0; u < NT; ++u) {
    const int p = u & 1;
    const unsigned short* sAh = &lds[p][0][wr][0];
    const unsigned short* sBh = &lds[p][1][wc >> 1][0];
    const int rb = (wc & 1) * 64;

    // ---- phase 1: B frags + A quad0; stage tile u+1 A-half1 ----
#pragma unroll
    for (int ni = 0; ni < 4; ++ni)
#pragma unroll
      for (int kk = 0; kk < 2; ++kk)
        bfr[ni][kk] = ld_frag(sBh, rb + ni * 16 + r, kk * 64 + q4 * 16);
    read_aq<0>(a0, sAh, r, q4);
    if (u + 1 < NT)
      STAGE(&lds[p ^ 1][0][1][0], Abase + (size_t)128 * K + (size_t)(u + 1) * BKT);
    LGKM_HINT(8);   // start draining the 12-read burst before the barrier
    BAR();
    WAIT_LGKM0();
    mfma_quad<0>(acc, a0, bfr);
    BAR();

    // ---- phase 2: A quads 1,2; stage tile u+2 B-half0 (freed after p1) ----
    read_aq<2>(a1, sAh, r, q4);
    read_aq<4>(a2, sAh, r, q4);
    if (u + 2 < NT)
      STAGE(&lds[p][1][0][0], Bbase + (size_t)(u + 2) * BKT);
    BAR();
    WAIT_LGKM0();
    mfma_quad<2>(acc, a1, bfr);
    BAR();

    // ---- phase 3: A quad3; stage tile u+2 B-half1 ----
    read_aq<6>(a3, sAh, r, q4);
    if (u + 2 < NT)
      STAGE(&lds[p][1][1][0], Bbase + (size_t)128 * K + (size_t)(u + 2) * BKT);
    BAR();
    WAIT_LGKM0();
    mfma_quad<4>(acc, a2, bfr);
    BAR();

    // ---- phase 4: stage tile u+2 A-half0 (A reads done by p3); vmcnt ----
    if (u + 2 < NT)
      STAGE(&lds[p][0][0][0], Abase + (size_t)(u + 2) * BKT);
    if (u < NT - 1) {
      if (u + 2 < NT) { WAIT_VM(6); } else { WAIT_VM(0); }
    }
    BAR();
    WAIT_LGKM0();
    mfma_quad<6>(acc, a3, bfr);
    BAR();
  }

  // ---- epilogue: out = acc * scales + bias --------------------------------
  float sc[4], bs[4];
#pragma unroll
  for (int ni = 0; ni < 4; ++ni) {
    int col = bn + wc * 64 + ni * 16 + r;
    sc[ni] = scales[col];
    bs[ni] = bias[col];
  }
#pragma unroll
  for (int mi = 0; mi < 8; ++mi)
#pragma unroll
    for (int ni = 0; ni < 4; ++ni)
#pragma unroll
      for (int i = 0; i < 4; ++i) {
        int grow = bm + wr * 128 + mi * 16 + q4 * 4 + i;
        int gcol = bn + wc * 64 + ni * 16 + r;
        out[(size_t)grow * N + gcol] = acc[mi][ni][i] * sc[ni] + bs[ni];
      }
}

// ---- fallback (correct but slow) ------------------------------------------
__global__ __launch_bounds__(256) void naive_kernel(
    const float* __restrict__ A, const int* __restrict__ W8,
    const float* __restrict__ scales, const float* __restrict__ bias,
    float* __restrict__ out, int M, int N, int K) {
  long idx = (long)blockIdx.x * 256 + threadIdx.x;
  if (idx >= (long)M * N) return;
  int m = (int)(idx / N), n = (int)(idx % N);
  const float* a = A + (size_t)m * K;
  const int* wv = W8 + (size_t)n * K;
  float s = 0.f;
  for (int k = 0; k < K; ++k) s += a[k] * (float)wv[k];
  out[idx] = s * scales[n] + bias[n];
}

extern "C" void kernel_launch(void* const* d_in, const int* in_sizes, int n_in,
                              void* d_out, int out_size, void* d_ws, size_t ws_size,
                              hipStream_t stream) {
  const float* A = (const float*)d_in[0];
  const int* W8 = (const int*)d_in[1];
  const float* scales = (const float*)d_in[2];
  const float* bias = (const float*)d_in[3];
  float* out = (float*)d_out;

  const int N = in_sizes[2];
  const int K = in_sizes[1] / N;
  const int M = in_sizes[0] / K;

  size_t a_bytes = (size_t)M * K * 2;
  size_t w_bytes = (size_t)N * K * 2;

  bool tiled_ok = (M % BM == 0) && (N % BN == 0) && (K % BKT == 0) &&
                  (K / BKT >= 3) && (ws_size >= a_bytes + w_bytes);

  if (!tiled_ok) {
    long total = (long)M * N;
    naive_kernel<<<(unsigned)((total + 255) / 256), 256, 0, stream>>>(
        A, W8, scales, bias, out, M, N, K);
    return;
  }

  unsigned short* Abf = (unsigned short*)d_ws;
  unsigned short* Wbf = (unsigned short*)((char*)d_ws + a_bytes);

  long nA = (long)M * K;
  long nW = (long)N * K;
  cvt_a_kernel<<<(unsigned)(nA / 2048), 256, 0, stream>>>(A, Abf);
  cvt_w_kernel<<<(unsigned)(nW / 2048), 256, 0, stream>>>(W8, Wbf);

  unsigned nwg = (unsigned)((M / BM) * (N / BN));  // 512
  gemm8_kernel<<<nwg, 512, 0, stream>>>(Abf, Wbf, scales, bias, out, M, N, K);
}